// Round 10
// baseline (83.582 us; speedup 1.0000x reference)
//
#include <hip/hip_runtime.h>
#include <cstddef>

#define BB 64
#define MM 5
#define NN 1000
#define DD 128
#define HH 8
#define KSZ 16
#define NCH 16       // k2 chunks per b (all-h blocks, 2 heads per wave)
#define CH2 63       // k2 chunk size (16*63 = 1008 >= 1000, guarded)
#define NC3 16       // k3 chunks per b
#define CH3 63       // k3 chunk size
#define INV_SQRT_D 0.08838834764831845f

__device__ __forceinline__ float tanh_fast(float x) {
  float e = __expf(2.f * x);
  return 1.f - 2.f / (e + 1.f);   // safe at +/-inf
}

// ---------------- k1: blocks [0,256): (b, d-quarter) query projection.
// Blocks [256,320): pack feasibility mask bits -> pmask[b][n].
__global__ __launch_bounds__(256) void k1_query(
    const float* __restrict__ fc, const float* __restrict__ pne,
    const float* __restrict__ vdf, const float* __restrict__ wpcv,
    const float* __restrict__ wpns, const int* __restrict__ mask,
    float* __restrict__ q_ws, float* __restrict__ qw_ws,
    unsigned int* __restrict__ pmask)
{
  const int t = threadIdx.x;
  if (blockIdx.x >= BB * 4) {          // mask-pack blocks
    const int b = blockIdx.x - BB * 4;
    const int* mb = mask + (size_t)(b * MM) * NN;
    for (int n = t; n < NN; n += 256) {
      unsigned int pm = 0;
#pragma unroll
      for (int m = 0; m < MM; ++m) pm |= (mb[m * NN + n] != 0 ? 1u : 0u) << m;
      pmask[b * NN + n] = pm;
    }
    return;
  }
  const int b = blockIdx.x >> 2;
  const int dq = blockIdx.x & 3;
  const int k = t & 15, gid = t >> 4;  // 16 groups of 16 lanes
  __shared__ float qsh[MM][32];

  float cvr[9];
  int curm = -1;
  for (int r = 0; r < 10; ++r) {       // r = m*2 + dhalf
    const int m = r >> 1;
    if (m != curm) {
      curm = m;
      const float* pner = pne + (size_t)(b * MM + m) * DD;
#pragma unroll
      for (int jp = 0; jp < 8; ++jp) cvr[jp] = pner[k + 16 * jp];
      cvr[8] = (k < 3) ? vdf[(b * MM + m) * 3 + k] : 0.f;
    }
    const int dl = (r & 1) * 16 + gid;
    const int d = dq * 32 + dl;
    const float* wrow = wpcv + d * 131;
    float p = 0.f;
#pragma unroll
    for (int jp = 0; jp < 8; ++jp) p = fmaf(cvr[jp], wrow[k + 16 * jp], p);
    if (k < 3) p = fmaf(cvr[8], wrow[128 + k], p);
    p += __shfl_xor(p, 1); p += __shfl_xor(p, 2);
    p += __shfl_xor(p, 4); p += __shfl_xor(p, 8);
    if (k == 0) {
      const float q = 0.25f * (p + fc[b * DD + d]);   // fold 1/sqrt(KS)
      qsh[m][dl] = q;
      q_ws[(size_t)(b * MM + m) * DD + d] = q;
    }
  }
  __syncthreads();
  if (t < 80) {
    const int hh = t / 40;             // 0/1 within this quarter
    const int r = t - hh * 40, m = r >> 3, f = r & 7;
    const int h = dq * 2 + hh;
    float acc = 0.f;
#pragma unroll
    for (int kk = 0; kk < KSZ; ++kk)
      acc = fmaf(qsh[m][hh * 16 + kk], wpns[(DD + h * KSZ + kk) * 8 + f], acc);
    qw_ws[(b * HH + h) * 40 + m * 8 + f] = acc;
  }
}

// ---------------- k2: per (b, 63-chunk) ALL-HEAD partials; ndf staged ONCE.
// 4 waves x 2 heads each; 4-lane groups over n; per-wave butterfly only;
// low 4 lanes store the 121-float record straight to global (no LDS tail).
// XCD-affinity: bid = (b%8) + 8*((b/8)*16 + c).
__global__ __launch_bounds__(256, 3) void k2_attn(
    const float* __restrict__ ndf, const float* __restrict__ gV,
    const float* __restrict__ gK, const unsigned int* __restrict__ pmask,
    const float* __restrict__ q_ws, const float* __restrict__ qw_ws,
    float* __restrict__ part)
{
  const int bid = blockIdx.x;
  const int xcd = bid & 7;
  const int rr = bid >> 3;
  const int c = rr & 15;
  const int b = (rr >> 4) * 8 + xcd;
  const int t = threadIdx.x;
  const int w = t >> 6;                // wave -> heads 2w, 2w+1
  const int lane = t & 63;
  const int k = t & 3;                 // kk-slot (K/V comps 4k..4k+3)
  const int gid = (t >> 2) & 15;       // n-slot within wave
  const int n0 = c * CH2;
  const int nvalid = (NN - n0 < CH2) ? (NN - n0) : CH2;   // 63 or 55

  __shared__ float nlds[CH2][MM][8];   // 10080 B
  __shared__ unsigned int pmlds[64];

  // stage ndf once (630 float4, coalesced 2016B runs per m) + pmask
  for (int i = t; i < CH2 * MM * 2; i += 256) {
    const int m = i / (CH2 * 2);
    const int r2 = i - m * (CH2 * 2);
    const int n = r2 >> 1, half = r2 & 1;
    const int ns = (n < nvalid) ? n : (nvalid - 1);
    const float4 v = *(const float4*)(ndf + ((size_t)(b * MM + m) * NN + n0 + ns) * 8 + 4 * half);
    *(float4*)(&nlds[n][m][4 * half]) = v;
  }
  for (int i = t; i < 64; i += 256)
    pmlds[i] = (i < nvalid) ? pmask[b * NN + n0 + i] : 0u;

  const int h0 = 2 * w, h1 = 2 * w + 1;
  float4 qr0[MM], qr1[MM];
  float2 qw0[MM], qw1[MM];
#pragma unroll
  for (int m = 0; m < MM; ++m) {
    qr0[m] = *(const float4*)(q_ws + (size_t)(b * MM + m) * DD + h0 * KSZ + 4 * k);
    qr1[m] = *(const float4*)(q_ws + (size_t)(b * MM + m) * DD + h1 * KSZ + 4 * k);
    qw0[m] = *(const float2*)(qw_ws + (b * HH + h0) * 40 + m * 8 + 2 * k);
    qw1[m] = *(const float2*)(qw_ws + (b * HH + h1) * 40 + m * 8 + 2 * k);
  }
  __syncthreads();

  const float* kb0 = gK + ((size_t)(h0 * BB + b) * NN + n0) * KSZ + 4 * k;
  const float* vb0 = gV + ((size_t)(h0 * BB + b) * NN + n0) * KSZ + 4 * k;
  const float* kb1 = gK + ((size_t)(h1 * BB + b) * NN + n0) * KSZ + 4 * k;
  const float* vb1 = gV + ((size_t)(h1 * BB + b) * NN + n0) * KSZ + 4 * k;

  float4 ha0[MM] = {}, ha1[MM] = {};
  float2 af0[MM] = {}, af1[MM] = {};
  float ls0 = 0.f, ls1 = 0.f;

#pragma unroll
  for (int i = 0; i < 4; ++i) {
    const int nl = gid + 16 * i;                 // 0..63
    const int nc = (nl < nvalid) ? nl : (nvalid - 1);
    const unsigned int pm = (nl < nvalid) ? pmlds[nl] : 0u;
    const float4 K0 = *(const float4*)(kb0 + nc * KSZ);
    const float4 V0 = *(const float4*)(vb0 + nc * KSZ);
    const float4 K1 = *(const float4*)(kb1 + nc * KSZ);
    const float4 V1 = *(const float4*)(vb1 + nc * KSZ);
    float2 nd[MM];
#pragma unroll
    for (int m = 0; m < MM; ++m) nd[m] = *(const float2*)(&nlds[nc][m][2 * k]);
#pragma unroll
    for (int m = 0; m < MM; ++m) {
      const float bit = ((pm >> m) & 1u) ? 1.f : 0.f;
      float p0 = K0.x * qr0[m].x + K0.y * qr0[m].y + K0.z * qr0[m].z + K0.w * qr0[m].w
               + nd[m].x * qw0[m].x + nd[m].y * qw0[m].y;
      p0 += __shfl_xor(p0, 1); p0 += __shfl_xor(p0, 2);
      const float e0 = bit * __expf(p0);
      ha0[m].x = fmaf(e0, V0.x, ha0[m].x);
      ha0[m].y = fmaf(e0, V0.y, ha0[m].y);
      ha0[m].z = fmaf(e0, V0.z, ha0[m].z);
      ha0[m].w = fmaf(e0, V0.w, ha0[m].w);
      af0[m].x = fmaf(e0, nd[m].x, af0[m].x);
      af0[m].y = fmaf(e0, nd[m].y, af0[m].y);
      ls0 += e0;
      float p1 = K1.x * qr1[m].x + K1.y * qr1[m].y + K1.z * qr1[m].z + K1.w * qr1[m].w
               + nd[m].x * qw1[m].x + nd[m].y * qw1[m].y;
      p1 += __shfl_xor(p1, 1); p1 += __shfl_xor(p1, 2);
      const float e1 = bit * __expf(p1);
      ha1[m].x = fmaf(e1, V1.x, ha1[m].x);
      ha1[m].y = fmaf(e1, V1.y, ha1[m].y);
      ha1[m].z = fmaf(e1, V1.z, ha1[m].z);
      ha1[m].w = fmaf(e1, V1.w, ha1[m].w);
      af1[m].x = fmaf(e1, nd[m].x, af1[m].x);
      af1[m].y = fmaf(e1, nd[m].y, af1[m].y);
      ls1 += e1;
    }
  }

  // per-wave butterfly across the 16 groups (k-slot preserved by xor>=4)
#pragma unroll
  for (int m = 0; m < MM; ++m) {
#pragma unroll
    for (int off = 4; off <= 32; off <<= 1) {
      ha0[m].x += __shfl_xor(ha0[m].x, off);
      ha0[m].y += __shfl_xor(ha0[m].y, off);
      ha0[m].z += __shfl_xor(ha0[m].z, off);
      ha0[m].w += __shfl_xor(ha0[m].w, off);
      af0[m].x += __shfl_xor(af0[m].x, off);
      af0[m].y += __shfl_xor(af0[m].y, off);
      ha1[m].x += __shfl_xor(ha1[m].x, off);
      ha1[m].y += __shfl_xor(ha1[m].y, off);
      ha1[m].z += __shfl_xor(ha1[m].z, off);
      ha1[m].w += __shfl_xor(ha1[m].w, off);
      af1[m].x += __shfl_xor(af1[m].x, off);
      af1[m].y += __shfl_xor(af1[m].y, off);
    }
  }
#pragma unroll
  for (int off = 4; off <= 32; off <<= 1) {
    ls0 += __shfl_xor(ls0, off);
    ls1 += __shfl_xor(ls1, off);
  }

  // low 4 lanes of each wave store both head records directly
  if (lane < 4) {
    float* P0 = part + (size_t)((b * NCH + c) * HH + h0) * 128;
    float* P1 = part + (size_t)((b * NCH + c) * HH + h1) * 128;
#pragma unroll
    for (int m = 0; m < MM; ++m) {
      *(float4*)(P0 + m * 16 + 4 * k) = ha0[m];
      *(float4*)(P1 + m * 16 + 4 * k) = ha1[m];
      *(float2*)(P0 + 80 + m * 8 + 2 * k) = af0[m];
      *(float2*)(P1 + 80 + m * 8 + 2 * k) = af1[m];
    }
    if (k == 0) { P0[120] = ls0; P1[120] = ls1; }
  }
}

// ---------------- k2b: per-b combine chunks -> conc -> fq (prescaled), fw
__global__ __launch_bounds__(256) void k2b_combine(
    const float* __restrict__ part, const float* __restrict__ wpns,
    const float* __restrict__ po, float* __restrict__ fq_ws,
    float* __restrict__ fw_ws)
{
  const int b = blockIdx.x;
  const int t = threadIdx.x;
  __shared__ float pos[DD][129];   // stride 129: conflict-free column reads
  __shared__ float rgs[HH];
  __shared__ float afs[HH][MM][8];
  __shared__ float cs[MM][DD];
  __shared__ float fqs[MM][DD];

  for (int i = t; i < DD * DD / 4; i += 256) {
    const float4 v = ((const float4*)po)[i];
    const int r = (i * 4) >> 7, cc = (i * 4) & 127;
    pos[r][cc] = v.x; pos[r][cc + 1] = v.y; pos[r][cc + 2] = v.z; pos[r][cc + 3] = v.w;
  }
  const float* pb = part + (size_t)b * NCH * HH * 128;
  if (t < HH) {
    float s = 0.f;
#pragma unroll
    for (int c = 0; c < NCH; ++c) s += pb[(c * HH + t) * 128 + 120];
    rgs[t] = 1.f / s;
  }
  // HH*MM*8 = 320 > 256 threads — strided loop required.
  for (int idx = t; idx < HH * MM * 8; idx += 256) {
    const int h = idx / 40, r = idx % 40;
    float a = 0.f;
#pragma unroll
    for (int c = 0; c < NCH; ++c) a += pb[(c * HH + h) * 128 + 80 + r];
    afs[h][r >> 3][r & 7] = a;
  }
  __syncthreads();
  for (int idx = t; idx < MM * DD; idx += 256) {
    const int m = idx >> 7, d = idx & 127, h = d >> 4;
    float a = 0.f;
#pragma unroll
    for (int c = 0; c < NCH; ++c) a += pb[(c * HH + h) * 128 + m * 16 + (d & 15)];
    float cf = 0.f;
#pragma unroll
    for (int f = 0; f < 8; ++f) cf = fmaf(wpns[d * 8 + f], afs[h][m][f], cf);
    cs[m][d] = (a + cf) * rgs[h];
  }
  __syncthreads();
  for (int idx = t; idx < MM * DD; idx += 256) {
    const int m = idx >> 7, d = idx & 127;
    float acc = 0.f;
#pragma unroll 8
    for (int j = 0; j < DD; ++j) acc = fmaf(cs[m][j], pos[d][j], acc);
    acc *= INV_SQRT_D;   // fold 1/sqrt(D)
    fqs[m][d] = acc;
    fq_ws[(size_t)b * (MM * DD) + idx] = acc;
  }
  __syncthreads();
  if (t < MM * 8) {
    const int m = t >> 3, f = t & 7;
    float acc = 0.f;
#pragma unroll 16
    for (int d = 0; d < DD; ++d) acc = fmaf(fqs[m][d], wpns[(2 * DD + d) * 8 + f], acc);
    fw_ws[b * 40 + t] = acc;
  }
}

// ---------------- k3: per (b,chunk) logits, 16-lane shfl-dot, direct exp.
__global__ __launch_bounds__(256, 4) void k3_logits(
    const float* __restrict__ ndf, const float* __restrict__ lK,
    const unsigned int* __restrict__ pmask, const float* __restrict__ fq_ws,
    const float* __restrict__ fw_ws, float* __restrict__ out,
    float* __restrict__ stats)
{
  const int b = blockIdx.x & 63;       // XCD-affinity for per-b shared data
  const int c = blockIdx.x >> 6;
  const int t = threadIdx.x;
  const int k = t & 15, gid = t >> 4;  // 16 groups of 16 lanes
  const int n0 = c * CH3;

  float4 fqr[MM][2];
  float fwr[MM];
#pragma unroll
  for (int m = 0; m < MM; ++m) {
    fqr[m][0] = *(const float4*)(fq_ws + (size_t)(b * MM + m) * DD + 8 * k);
    fqr[m][1] = *(const float4*)(fq_ws + (size_t)(b * MM + m) * DD + 8 * k + 4);
    fwr[m] = fw_ws[b * 40 + m * 8 + (k & 7)];
  }
  float lsum = 0.f;

#pragma unroll
  for (int half = 0; half < 2; ++half) {
    float4 l0[2], l1[2];
    float ndv[2][MM];
    unsigned int pm[2];
    int ng[2];
    bool vld[2];
#pragma unroll
    for (int j = 0; j < 2; ++j) {
      const int nl = gid + 16 * (half * 2 + j);
      const int n = n0 + nl;
      vld[j] = (nl < CH3) && (n < NN);   // group-uniform
      const int nc = vld[j] ? n : n0;
      ng[j] = nc;
      pm[j] = vld[j] ? pmask[b * NN + nc] : 0u;
      const float* lkr = lK + ((size_t)b * NN + nc) * DD;
      l0[j] = *(const float4*)(lkr + 8 * k);
      l1[j] = *(const float4*)(lkr + 8 * k + 4);
#pragma unroll
      for (int m = 0; m < MM; ++m)
        ndv[j][m] = (k < 8) ? ndf[((size_t)(b * MM + m) * NN + nc) * 8 + k] : 0.f;
    }
#pragma unroll
    for (int j = 0; j < 2; ++j) {
#pragma unroll
      for (int m = 0; m < MM; ++m) {
        float p = l0[j].x * fqr[m][0].x + l0[j].y * fqr[m][0].y
                + l0[j].z * fqr[m][0].z + l0[j].w * fqr[m][0].w
                + l1[j].x * fqr[m][1].x + l1[j].y * fqr[m][1].y
                + l1[j].z * fqr[m][1].z + l1[j].w * fqr[m][1].w
                + ndv[j][m] * fwr[m];
        p += __shfl_xor(p, 1); p += __shfl_xor(p, 2);
        p += __shfl_xor(p, 4); p += __shfl_xor(p, 8);
        const float e = ((pm[j] >> m) & 1u) ? __expf(tanh_fast(p) * 10.f) : 0.f;
        if (vld[j]) {
          lsum += e;
          if (k == 0) out[(size_t)(b * MM + m) * NN + ng[j]] = e;
        }
      }
    }
  }
  // per-lane lsum already holds its group's sum; xor16/32 sums the 4 groups.
  lsum += __shfl_xor(lsum, 16);
  lsum += __shfl_xor(lsum, 32);
  __shared__ float wred[4];
  if ((t & 63) == 0) wred[t >> 6] = lsum;
  __syncthreads();
  if (t == 0)
    stats[b * NC3 + c] = wred[0] + wred[1] + wred[2] + wred[3];
}

// ---------------- k4: per (b,m) scale row by 1/sum
__global__ __launch_bounds__(256) void k4_probs(
    const float* __restrict__ stats, float* __restrict__ out)
{
  const int bm = blockIdx.x;
  const int b = bm / MM;
  const int t = threadIdx.x;
  float s = 0.f;
#pragma unroll
  for (int c = 0; c < NC3; ++c) s += stats[b * NC3 + c];
  const float scale = 1.f / s;
  if (t < 250) {
    float4* p = (float4*)(out + (size_t)bm * NN);
    float4 v = p[t];
    v.x *= scale; v.y *= scale; v.z *= scale; v.w *= scale;
    p[t] = v;
  }
}

extern "C" void kernel_launch(void* const* d_in, const int* in_sizes, int n_in,
                              void* d_out, int out_size, void* d_ws, size_t ws_size,
                              hipStream_t stream) {
  // d_in[0] = node_embeddings: dead input, never read.
  const float* fc   = (const float*)d_in[1];
  const float* pne  = (const float*)d_in[2];
  const float* ndf  = (const float*)d_in[3];
  const float* vdf  = (const float*)d_in[4];
  const float* gV   = (const float*)d_in[5];
  const float* gK   = (const float*)d_in[6];
  const float* lK   = (const float*)d_in[7];
  const int*   mask = (const int*)d_in[8];
  const float* wpcv = (const float*)d_in[9];
  const float* wpns = (const float*)d_in[10];
  const float* po   = (const float*)d_in[11];

  float* q_ws  = (float*)d_ws;                        // 40960
  float* qw_ws = q_ws + BB * MM * DD;                 // 20480
  float* part  = qw_ws + BB * HH * 40;                // 64*16*8*128 = 1048576
  float* fq_ws = part + (size_t)BB * NCH * HH * 128;  // 40960
  float* fw_ws = fq_ws + BB * MM * DD;                // 2560
  float* stats = fw_ws + BB * 40;                     // 1024
  unsigned int* pmask = (unsigned int*)(stats + BB * NC3);  // 64000 u32
  float* out   = (float*)d_out;

  k1_query<<<BB * 4 + BB, 256, 0, stream>>>(fc, pne, vdf, wpcv, wpns, mask,
                                            q_ws, qw_ws, pmask);
  k2_attn<<<BB * NCH, 256, 0, stream>>>(ndf, gV, gK, pmask, q_ws, qw_ws, part);
  k2b_combine<<<BB, 256, 0, stream>>>(part, wpns, po, fq_ws, fw_ws);
  k3_logits<<<BB * NC3, 256, 0, stream>>>(ndf, lK, pmask, fq_ws, fw_ws, out, stats);
  k4_probs<<<BB * MM, 256, 0, stream>>>(stats, out);
}

// Round 11
// 56.904 us; speedup vs baseline: 1.4688x; 1.4688x over previous
//
#include <hip/hip_runtime.h>
#include <cstddef>

#define BB 64
#define MM 5
#define NN 1000
#define DD 128
#define HH 8
#define KSZ 16
#define NCH 4        // k2 chunks per b
#define CH2 250      // k2 chunk size
#define NC3 8        // k3 chunks per b
#define CH3 125      // k3 chunk size
#define INV_SQRT_D 0.08838834764831845f

__device__ __forceinline__ float tanh_fast(float x) {
  float e = __expf(2.f * x);
  return 1.f - 2.f / (e + 1.f);   // safe at +/-inf
}

// ---------------- k1: blocks [0,256): (b, d-quarter) query projection.
// Blocks [256,320): pack feasibility mask bits -> pmask[b][n].
__global__ __launch_bounds__(256) void k1_query(
    const float* __restrict__ fc, const float* __restrict__ pne,
    const float* __restrict__ vdf, const float* __restrict__ wpcv,
    const float* __restrict__ wpns, const int* __restrict__ mask,
    float* __restrict__ q_ws, float* __restrict__ qw_ws,
    unsigned int* __restrict__ pmask)
{
  const int t = threadIdx.x;
  if (blockIdx.x >= BB * 4) {          // mask-pack blocks
    const int b = blockIdx.x - BB * 4;
    const int* mb = mask + (size_t)(b * MM) * NN;
    for (int n = t; n < NN; n += 256) {
      unsigned int pm = 0;
#pragma unroll
      for (int m = 0; m < MM; ++m) pm |= (mb[m * NN + n] != 0 ? 1u : 0u) << m;
      pmask[b * NN + n] = pm;
    }
    return;
  }
  const int b = blockIdx.x >> 2;
  const int dq = blockIdx.x & 3;
  const int k = t & 15, gid = t >> 4;  // 16 groups of 16 lanes
  __shared__ float qsh[MM][32];

  float cvr[9];
  int curm = -1;
  for (int r = 0; r < 10; ++r) {       // r = m*2 + dhalf
    const int m = r >> 1;
    if (m != curm) {
      curm = m;
      const float* pner = pne + (size_t)(b * MM + m) * DD;
#pragma unroll
      for (int jp = 0; jp < 8; ++jp) cvr[jp] = pner[k + 16 * jp];
      cvr[8] = (k < 3) ? vdf[(b * MM + m) * 3 + k] : 0.f;
    }
    const int dl = (r & 1) * 16 + gid;
    const int d = dq * 32 + dl;
    const float* wrow = wpcv + d * 131;
    float p = 0.f;
#pragma unroll
    for (int jp = 0; jp < 8; ++jp) p = fmaf(cvr[jp], wrow[k + 16 * jp], p);
    if (k < 3) p = fmaf(cvr[8], wrow[128 + k], p);
    p += __shfl_xor(p, 1); p += __shfl_xor(p, 2);
    p += __shfl_xor(p, 4); p += __shfl_xor(p, 8);
    if (k == 0) {
      const float q = 0.25f * (p + fc[b * DD + d]);   // fold 1/sqrt(KS)
      qsh[m][dl] = q;
      q_ws[(size_t)(b * MM + m) * DD + d] = q;
    }
  }
  __syncthreads();
  if (t < 80) {
    const int hh = t / 40;             // 0/1 within this quarter
    const int r = t - hh * 40, m = r >> 3, f = r & 7;
    const int h = dq * 2 + hh;
    float acc = 0.f;
#pragma unroll
    for (int kk = 0; kk < KSZ; ++kk)
      acc = fmaf(qsh[m][hh * 16 + kk], wpns[(DD + h * KSZ + kk) * 8 + f], acc);
    qw_ws[(b * HH + h) * 40 + m * 8 + f] = acc;
  }
}

// ---------------- k2: per (b, chunk, head-PAIR) partials. 1024 blocks x 256.
// 4-lane groups over 64 n-slots; ndf/pmask loaded ONCE per pair (halves the
// dominant VMEM count per head); LDS-coalesced record stores (no scatter).
// part[((b*NCH+c)*HH)+h][m*16+kk]=sum e*V ; [80+m*8+f]=sum e*ndf ; [120]=sum e.
__global__ __launch_bounds__(256) void k2_attn(
    const float* __restrict__ ndf, const float* __restrict__ gV,
    const float* __restrict__ gK, const unsigned int* __restrict__ pmask,
    const float* __restrict__ q_ws, const float* __restrict__ qw_ws,
    float* __restrict__ part)
{
  const int bid = blockIdx.x;
  const int b = bid & 63;
  const int rest = bid >> 6;           // c*4 + p : blocks sharing (b,c) ndf are
  const int p = rest & 3;              // 64 bids apart -> same XCD (64%8==0)
  const int c = rest >> 2;
  const int h0 = 2 * p, h1 = 2 * p + 1;
  const int t = threadIdx.x;
  const int k = t & 3, gid = t >> 2;   // 64 groups of 4 lanes
  const int n0 = c * CH2;

  const float* kb0 = gK + ((size_t)(h0 * BB + b) * NN + n0) * KSZ + 4 * k;
  const float* vb0 = gV + ((size_t)(h0 * BB + b) * NN + n0) * KSZ + 4 * k;
  const float* kb1 = gK + ((size_t)(h1 * BB + b) * NN + n0) * KSZ + 4 * k;
  const float* vb1 = gV + ((size_t)(h1 * BB + b) * NN + n0) * KSZ + 4 * k;
  const float* nb = ndf + ((size_t)(b * MM) * NN + n0) * 8 + 2 * k;
  const unsigned int* pmb = pmask + b * NN + n0;

  float4 qr0[MM], qr1[MM];
  float2 qw0[MM], qw1[MM];
#pragma unroll
  for (int m = 0; m < MM; ++m) {
    qr0[m] = *(const float4*)(q_ws + (size_t)(b * MM + m) * DD + h0 * KSZ + 4 * k);
    qr1[m] = *(const float4*)(q_ws + (size_t)(b * MM + m) * DD + h1 * KSZ + 4 * k);
    qw0[m] = *(const float2*)(qw_ws + (b * HH + h0) * 40 + m * 8 + 2 * k);
    qw1[m] = *(const float2*)(qw_ws + (b * HH + h1) * 40 + m * 8 + 2 * k);
  }

  float4 ha0[MM] = {}, ha1[MM] = {};
  float2 af0[MM] = {}, af1[MM] = {};
  float ls0 = 0.f, ls1 = 0.f;

#pragma unroll
  for (int i = 0; i < 4; ++i) {
    const int nl = gid + 64 * i;
    const bool valid = (i < 3) || (gid < CH2 - 192);   // group-uniform
    const int nc = valid ? nl : 0;
    const unsigned int pm = valid ? pmb[nc] : 0u;
    const float4 K0 = *(const float4*)(kb0 + nc * KSZ);
    const float4 V0 = *(const float4*)(vb0 + nc * KSZ);
    const float4 K1 = *(const float4*)(kb1 + nc * KSZ);
    const float4 V1 = *(const float4*)(vb1 + nc * KSZ);
    float2 nd[MM];
#pragma unroll
    for (int m = 0; m < MM; ++m)
      nd[m] = *(const float2*)(nb + ((size_t)m * NN + nc) * 8);
#pragma unroll
    for (int m = 0; m < MM; ++m) {
      const float bit = ((pm >> m) & 1u) ? 1.f : 0.f;
      float p0 = K0.x * qr0[m].x + K0.y * qr0[m].y + K0.z * qr0[m].z + K0.w * qr0[m].w
               + nd[m].x * qw0[m].x + nd[m].y * qw0[m].y;
      float p1 = K1.x * qr1[m].x + K1.y * qr1[m].y + K1.z * qr1[m].z + K1.w * qr1[m].w
               + nd[m].x * qw1[m].x + nd[m].y * qw1[m].y;
      p0 += __shfl_xor(p0, 1); p0 += __shfl_xor(p0, 2);
      p1 += __shfl_xor(p1, 1); p1 += __shfl_xor(p1, 2);
      const float e0 = bit * __expf(p0);
      const float e1 = bit * __expf(p1);
      ha0[m].x = fmaf(e0, V0.x, ha0[m].x);
      ha0[m].y = fmaf(e0, V0.y, ha0[m].y);
      ha0[m].z = fmaf(e0, V0.z, ha0[m].z);
      ha0[m].w = fmaf(e0, V0.w, ha0[m].w);
      af0[m].x = fmaf(e0, nd[m].x, af0[m].x);
      af0[m].y = fmaf(e0, nd[m].y, af0[m].y);
      ls0 += e0;
      ha1[m].x = fmaf(e1, V1.x, ha1[m].x);
      ha1[m].y = fmaf(e1, V1.y, ha1[m].y);
      ha1[m].z = fmaf(e1, V1.z, ha1[m].z);
      ha1[m].w = fmaf(e1, V1.w, ha1[m].w);
      af1[m].x = fmaf(e1, nd[m].x, af1[m].x);
      af1[m].y = fmaf(e1, nd[m].y, af1[m].y);
      ls1 += e1;
    }
  }

  // wave butterfly across the 16 groups (k-slot preserved by xor>=4)
#pragma unroll
  for (int off = 4; off <= 32; off <<= 1) {
#pragma unroll
    for (int m = 0; m < MM; ++m) {
      ha0[m].x += __shfl_xor(ha0[m].x, off);
      ha0[m].y += __shfl_xor(ha0[m].y, off);
      ha0[m].z += __shfl_xor(ha0[m].z, off);
      ha0[m].w += __shfl_xor(ha0[m].w, off);
      af0[m].x += __shfl_xor(af0[m].x, off);
      af0[m].y += __shfl_xor(af0[m].y, off);
      ha1[m].x += __shfl_xor(ha1[m].x, off);
      ha1[m].y += __shfl_xor(ha1[m].y, off);
      ha1[m].z += __shfl_xor(ha1[m].z, off);
      ha1[m].w += __shfl_xor(ha1[m].w, off);
      af1[m].x += __shfl_xor(af1[m].x, off);
      af1[m].y += __shfl_xor(af1[m].y, off);
    }
    ls0 += __shfl_xor(ls0, off);
    ls1 += __shfl_xor(ls1, off);
  }

  __shared__ float redh[4][2][MM][KSZ];
  __shared__ float redaf[4][2][MM][8];
  __shared__ float reds[4][2];
  const int w = t >> 6;
  if ((t & 63) < 4) {
    const int kk = t & 3;
#pragma unroll
    for (int m = 0; m < MM; ++m) {
      *(float4*)(&redh[w][0][m][4 * kk]) = ha0[m];
      *(float4*)(&redh[w][1][m][4 * kk]) = ha1[m];
      *(float2*)(&redaf[w][0][m][2 * kk]) = af0[m];
      *(float2*)(&redaf[w][1][m][2 * kk]) = af1[m];
    }
    if (kk == 0) { reds[w][0] = ls0; reds[w][1] = ls1; }
  }
  __syncthreads();
  float* P = part + (size_t)((b * NCH + c) * HH) * 128;
  if (t < 160) {
    const int hp = t / 80, r = t - hp * 80;   // hp: 0->h0, 1->h1
    const int m = r >> 4, kk = r & 15;
    P[(hp ? h1 : h0) * 128 + r] =
        redh[0][hp][m][kk] + redh[1][hp][m][kk] +
        redh[2][hp][m][kk] + redh[3][hp][m][kk];
  } else if (t < 240) {
    const int r2 = t - 160;
    const int hp = r2 / 40, r = r2 - hp * 40;
    const int m = r >> 3, f = r & 7;
    P[(hp ? h1 : h0) * 128 + 80 + r] =
        redaf[0][hp][m][f] + redaf[1][hp][m][f] +
        redaf[2][hp][m][f] + redaf[3][hp][m][f];
  } else if (t == 240) {
    P[h0 * 128 + 120] = reds[0][0] + reds[1][0] + reds[2][0] + reds[3][0];
  } else if (t == 241) {
    P[h1 * 128 + 120] = reds[0][1] + reds[1][1] + reds[2][1] + reds[3][1];
  }
}

// ---------------- k3: per (b,chunk). Fused: combine partials -> conc -> fq,fw
// then streaming logits -> e-values. part layout: pb[(cc*HH+h)*128 + ...].
__global__ __launch_bounds__(512) void k3_logits(
    const float* __restrict__ ndf, const float* __restrict__ lK,
    const unsigned int* __restrict__ pmask, const float* __restrict__ part,
    const float* __restrict__ wpns, const float* __restrict__ po,
    float* __restrict__ out, float* __restrict__ stats)
{
  const int b = blockIdx.x >> 3;
  const int c = blockIdx.x & 7;
  const int t = threadIdx.x;

  __shared__ float pos[DD][129];   // stride 129: conflict-free column reads
  __shared__ float rgs[HH];
  __shared__ float afs[HH][MM][8];
  __shared__ float cs[MM][DD];
  __shared__ float fqs[MM][DD];
  __shared__ float fw[MM][8];
  __shared__ float wred[8];

  // ---- stage po (coalesced) + per-h sums + AF combine
  for (int i = t; i < DD * DD / 4; i += 512) {
    const float4 v = ((const float4*)po)[i];
    const int r = (i * 4) >> 7, cc = (i * 4) & 127;
    pos[r][cc] = v.x; pos[r][cc + 1] = v.y; pos[r][cc + 2] = v.z; pos[r][cc + 3] = v.w;
  }
  const float* pb = part + (size_t)b * NCH * HH * 128;
  if (t < HH) {
    float s = 0.f;
#pragma unroll
    for (int cc = 0; cc < NCH; ++cc) s += pb[(cc * HH + t) * 128 + 120];
    rgs[t] = 1.f / s;
  }
  if (t < HH * MM * 8) {
    const int h = t / 40, r = t % 40;
    float a = 0.f;
#pragma unroll
    for (int cc = 0; cc < NCH; ++cc) a += pb[(cc * HH + h) * 128 + 80 + r];
    afs[h][r >> 3][r & 7] = a;
  }
  __syncthreads();
  // ---- conc
  for (int idx = t; idx < MM * DD; idx += 512) {
    const int m = idx >> 7, d = idx & 127, h = d >> 4;
    float a = 0.f;
#pragma unroll
    for (int cc = 0; cc < NCH; ++cc) a += pb[(cc * HH + h) * 128 + m * 16 + (d & 15)];
    float cf = 0.f;
#pragma unroll
    for (int f = 0; f < 8; ++f) cf = fmaf(wpns[d * 8 + f], afs[h][m][f], cf);
    cs[m][d] = (a + cf) * rgs[h];
  }
  __syncthreads();
  // ---- fq = conc @ po.T (prescaled by 1/sqrt(D))
  for (int idx = t; idx < MM * DD; idx += 512) {
    const int m = idx >> 7, d = idx & 127;
    float acc = 0.f;
#pragma unroll 8
    for (int j = 0; j < DD; ++j) acc = fmaf(cs[m][j], pos[d][j], acc);
    fqs[m][d] = acc * INV_SQRT_D;
  }
  __syncthreads();
  // ---- fw
  if (t < MM * 8) {
    const int m = t >> 3, f = t & 7;
    float acc = 0.f;
#pragma unroll 16
    for (int d = 0; d < DD; ++d) acc = fmaf(fqs[m][d], wpns[(2 * DD + d) * 8 + f], acc);
    fw[m][f] = acc;
  }
  __syncthreads();

  // ---- streaming logits (16-lane shfl-dot, direct exp)
  const int k = t & 15, gid = t >> 4;   // 32 groups of 16 lanes
  const int n0 = c * CH3;
  float4 fqr[MM][2];
  float fwr[MM];
#pragma unroll
  for (int m = 0; m < MM; ++m) {
    fqr[m][0] = *(const float4*)(&fqs[m][8 * k]);
    fqr[m][1] = *(const float4*)(&fqs[m][8 * k + 4]);
    fwr[m] = fw[m][k & 7];
  }
  float lsum = 0.f;

#pragma unroll
  for (int i = 0; i < 4; ++i) {
    const int nl = gid + 32 * i;
    const bool valid = (nl < CH3);          // group-uniform
    const int n = n0 + (valid ? nl : 0);
    const unsigned int pm = valid ? pmask[b * NN + n] : 0u;
    const float* lkr = lK + ((size_t)b * NN + n) * DD;
    const float4 l0 = *(const float4*)(lkr + 8 * k);
    const float4 l1 = *(const float4*)(lkr + 8 * k + 4);
    float ndv[MM];
#pragma unroll
    for (int m = 0; m < MM; ++m)
      ndv[m] = (k < 8) ? ndf[((size_t)(b * MM + m) * NN + n) * 8 + k] : 0.f;
#pragma unroll
    for (int m = 0; m < MM; ++m) {
      float p = l0.x * fqr[m][0].x + l0.y * fqr[m][0].y
              + l0.z * fqr[m][0].z + l0.w * fqr[m][0].w
              + l1.x * fqr[m][1].x + l1.y * fqr[m][1].y
              + l1.z * fqr[m][1].z + l1.w * fqr[m][1].w
              + ndv[m] * fwr[m];
      p += __shfl_xor(p, 1); p += __shfl_xor(p, 2);
      p += __shfl_xor(p, 4); p += __shfl_xor(p, 8);
      const float e = ((pm >> m) & 1u) ? __expf(tanh_fast(p) * 10.f) : 0.f;
      if (valid) {
        lsum += e;
        if (k == 0) out[(size_t)(b * MM + m) * NN + n] = e;
      }
    }
  }
  // per-lane lsum already holds its group's sum; xor16/32 sums the 4 groups.
  lsum += __shfl_xor(lsum, 16);
  lsum += __shfl_xor(lsum, 32);
  if ((t & 63) == 0) wred[t >> 6] = lsum;
  __syncthreads();
  if (t == 0) {
    float s = 0.f;
#pragma unroll
    for (int w = 0; w < 8; ++w) s += wred[w];
    stats[b * NC3 + c] = s;
  }
}

// ---------------- k4: per (b,m) scale row by 1/sum
__global__ __launch_bounds__(256) void k4_probs(
    const float* __restrict__ stats, float* __restrict__ out)
{
  const int bm = blockIdx.x;
  const int b = bm / MM;
  const int t = threadIdx.x;
  float s = 0.f;
#pragma unroll
  for (int c = 0; c < NC3; ++c) s += stats[b * NC3 + c];
  const float scale = 1.f / s;
  if (t < 250) {
    float4* p = (float4*)(out + (size_t)bm * NN);
    float4 v = p[t];
    v.x *= scale; v.y *= scale; v.z *= scale; v.w *= scale;
    p[t] = v;
  }
}

extern "C" void kernel_launch(void* const* d_in, const int* in_sizes, int n_in,
                              void* d_out, int out_size, void* d_ws, size_t ws_size,
                              hipStream_t stream) {
  // d_in[0] = node_embeddings: dead input, never read.
  const float* fc   = (const float*)d_in[1];
  const float* pne  = (const float*)d_in[2];
  const float* ndf  = (const float*)d_in[3];
  const float* vdf  = (const float*)d_in[4];
  const float* gV   = (const float*)d_in[5];
  const float* gK   = (const float*)d_in[6];
  const float* lK   = (const float*)d_in[7];
  const int*   mask = (const int*)d_in[8];
  const float* wpcv = (const float*)d_in[9];
  const float* wpns = (const float*)d_in[10];
  const float* po   = (const float*)d_in[11];

  float* q_ws  = (float*)d_ws;                        // 40960
  float* qw_ws = q_ws + BB * MM * DD;                 // 20480
  float* part  = qw_ws + BB * HH * 40;                // 64*4*8*128 = 262144
  float* stats = part + (size_t)BB * NCH * HH * 128;  // 512
  unsigned int* pmask = (unsigned int*)(stats + BB * NC3);  // 64000 u32
  float* out   = (float*)d_out;

  k1_query<<<BB * 4 + BB, 256, 0, stream>>>(fc, pne, vdf, wpcv, wpns, mask,
                                            q_ws, qw_ws, pmask);
  k2_attn<<<BB * 2 * HH, 256, 0, stream>>>(ndf, gV, gK, pmask, q_ws, qw_ws, part);
  k3_logits<<<BB * NC3, 512, 0, stream>>>(ndf, lK, pmask, part, wpns, po, out, stats);
  k4_probs<<<BB * MM, 256, 0, stream>>>(stats, out);
}

// Round 12
// 56.777 us; speedup vs baseline: 1.4721x; 1.0022x over previous
//
#include <hip/hip_runtime.h>
#include <cstddef>

#define BB 64
#define MM 5
#define NN 1000
#define DD 128
#define HH 8
#define KSZ 16
#define NT 8         // k2 tiles per (b,h), 125 n each
#define TN 125
#define NC3 8        // k3 chunks per b
#define CH3 125      // k3 chunk size
#define INV_SQRT_D 0.08838834764831845f

// k2 LDS tile regions (bytes)
#define K2_KOFF 0
#define K2_VOFF 8192
#define K2_NOFF 16384
#define K2_POFF 36864
#define K2_BUF  37376

typedef __attribute__((address_space(1))) const void gconst_t;
typedef __attribute__((address_space(3))) void lds_t;
#define GLD16(src, dst) __builtin_amdgcn_global_load_lds((gconst_t*)(src), (lds_t*)(dst), 16, 0, 0)
#define GLD4(src, dst)  __builtin_amdgcn_global_load_lds((gconst_t*)(src), (lds_t*)(dst), 4, 0, 0)
#define VMCNT0() asm volatile("s_waitcnt vmcnt(0)" ::: "memory")

__device__ __forceinline__ float tanh_fast(float x) {
  float e = __expf(2.f * x);
  return 1.f - 2.f / (e + 1.f);   // safe at +/-inf
}

// ---------------- k1: blocks [0,256): (b, d-quarter) query projection.
// Blocks [256,320): pack feasibility mask bits -> pmask[b][n].
__global__ __launch_bounds__(256) void k1_query(
    const float* __restrict__ fc, const float* __restrict__ pne,
    const float* __restrict__ vdf, const float* __restrict__ wpcv,
    const float* __restrict__ wpns, const int* __restrict__ mask,
    float* __restrict__ q_ws, float* __restrict__ qw_ws,
    unsigned int* __restrict__ pmask)
{
  const int t = threadIdx.x;
  if (blockIdx.x >= BB * 4) {          // mask-pack blocks
    const int b = blockIdx.x - BB * 4;
    const int* mb = mask + (size_t)(b * MM) * NN;
    for (int n = t; n < NN; n += 256) {
      unsigned int pm = 0;
#pragma unroll
      for (int m = 0; m < MM; ++m) pm |= (mb[m * NN + n] != 0 ? 1u : 0u) << m;
      pmask[b * NN + n] = pm;
    }
    return;
  }
  const int b = blockIdx.x >> 2;
  const int dq = blockIdx.x & 3;
  const int k = t & 15, gid = t >> 4;  // 16 groups of 16 lanes
  __shared__ float qsh[MM][32];

  float cvr[9];
  int curm = -1;
  for (int r = 0; r < 10; ++r) {       // r = m*2 + dhalf
    const int m = r >> 1;
    if (m != curm) {
      curm = m;
      const float* pner = pne + (size_t)(b * MM + m) * DD;
#pragma unroll
      for (int jp = 0; jp < 8; ++jp) cvr[jp] = pner[k + 16 * jp];
      cvr[8] = (k < 3) ? vdf[(b * MM + m) * 3 + k] : 0.f;
    }
    const int dl = (r & 1) * 16 + gid;
    const int d = dq * 32 + dl;
    const float* wrow = wpcv + d * 131;
    float p = 0.f;
#pragma unroll
    for (int jp = 0; jp < 8; ++jp) p = fmaf(cvr[jp], wrow[k + 16 * jp], p);
    if (k < 3) p = fmaf(cvr[8], wrow[128 + k], p);
    p += __shfl_xor(p, 1); p += __shfl_xor(p, 2);
    p += __shfl_xor(p, 4); p += __shfl_xor(p, 8);
    if (k == 0) {
      const float q = 0.25f * (p + fc[b * DD + d]);   // fold 1/sqrt(KS)
      qsh[m][dl] = q;
      q_ws[(size_t)(b * MM + m) * DD + d] = q;
    }
  }
  __syncthreads();
  if (t < 80) {
    const int hh = t / 40;             // 0/1 within this quarter
    const int r = t - hh * 40, m = r >> 3, f = r & 7;
    const int h = dq * 2 + hh;
    float acc = 0.f;
#pragma unroll
    for (int kk = 0; kk < KSZ; ++kk)
      acc = fmaf(qsh[m][hh * 16 + kk], wpns[(DD + h * KSZ + kk) * 8 + f], acc);
    qw_ws[(b * HH + h) * 40 + m * 8 + f] = acc;
  }
}

// ---------------- k2: per (b,h). Double-buffered global_load_lds streaming.
// 512 blocks x 256 thr (2 blocks/CU, ~75 KB LDS). 8 tiles of 125 n:
// stage(t+1) async while computing tile t from LDS; raw s_barrier + vmcnt(0)
// (NOT __syncthreads — it would drain the async queue). bid = h*64+b keeps
// all h-blocks of a batch on one XCD so ndf 8x re-reads are L2-hits.
// One output record per (b,h): [m*16+kk]=sum e*V ; [80+m*8+f]=sum e*ndf ; [120]=sum e.
__global__ __launch_bounds__(256, 2) void k2_attn(
    const float* __restrict__ ndf, const float* __restrict__ gV,
    const float* __restrict__ gK, const unsigned int* __restrict__ pmask,
    const float* __restrict__ q_ws, const float* __restrict__ qw_ws,
    float* __restrict__ part)
{
  const int bid = blockIdx.x;          // h*64 + b  -> xcd = b%8
  const int b = bid & 63;
  const int h = bid >> 6;
  const int t = threadIdx.x;
  const int w = t >> 6, lane = t & 63;
  const int k = t & 3, g = t >> 2;     // 64 groups of 4 lanes

  __shared__ __align__(16) char smem[2][K2_BUF];
  __shared__ float redh[4][MM][KSZ];
  __shared__ float redaf[4][MM][8];
  __shared__ float reds[4];

  const char* gkrow = (const char*)gK + (size_t)(h * BB + b) * (NN * 64);
  const char* gvrow = (const char*)gV + (size_t)(h * BB + b) * (NN * 64);
  const char* pmrow = (const char*)pmask + (size_t)b * (NN * 4);
  const char* ndrow0 = (const char*)ndf + (size_t)(b * MM) * (NN * 32);

  // stage tile tt into buffer bb: wave w issues segs {4j+w}, 38 segs total
  auto stage = [&](int tt, int bb) {
    char* base = smem[bb];
#pragma unroll
    for (int j = 0; j < 10; ++j) {
      const int seg = 4 * j + w;
      if (seg >= 38) continue;
      if (seg < 16) {                  // K (0..7) / V (8..15): 8000B/tile
        const int s = seg & 7;
        int off = tt * 8000 + s * 1024;
        if (off > NN * 64 - 1024) off = NN * 64 - 1024;   // row-local clamp
        const char* srow = (seg < 8) ? gkrow : gvrow;
        const int roff = (seg < 8) ? K2_KOFF : K2_VOFF;
        GLD16(srow + off + lane * 16, base + roff + (off - tt * 8000));
      } else if (seg < 36) {           // ndf: 5 rows x 4000B/tile
        const int rel = seg - 16, m = rel >> 2, q = rel & 3;
        int off = tt * 4000 + q * 1024;
        if (off > NN * 32 - 1024) off = NN * 32 - 1024;
        GLD16(ndrow0 + (size_t)m * (NN * 32) + off + lane * 16,
              base + K2_NOFF + m * 4096 + (off - tt * 4000));
      } else {                         // pmask: 500B/tile (waves 0,1)
        const int i4 = seg - 36;
        int off = tt * 500 + i4 * 256;
        if (off > NN * 4 - 256) off = NN * 4 - 256;
        GLD4(pmrow + off + lane * 4, base + K2_POFF + (off - tt * 500));
      }
    }
  };

  float4 qr[MM];
  float2 qw[MM];
#pragma unroll
  for (int m = 0; m < MM; ++m) {
    qr[m] = *(const float4*)(q_ws + (size_t)(b * MM + m) * DD + h * KSZ + 4 * k);
    qw[m] = *(const float2*)(qw_ws + (b * HH + h) * 40 + m * 8 + 2 * k);
  }

  float4 ha[MM] = {};
  float2 af[MM] = {};
  float ls = 0.f;

  stage(0, 0);
  VMCNT0();
  __builtin_amdgcn_s_barrier();

  for (int tt = 0; tt < NT; ++tt) {
    const int cur = tt & 1;
    if (tt < NT - 1) stage(tt + 1, cur ^ 1);
    const char* base = smem[cur];
#pragma unroll
    for (int i = 0; i < 2; ++i) {
      const int n = g + 64 * i;
      if (i == 0 || g < TN - 64) {
        const float4 kv = *(const float4*)(base + K2_KOFF + n * 64 + k * 16);
        const float4 vv = *(const float4*)(base + K2_VOFF + n * 64 + k * 16);
        const unsigned int pm = *(const unsigned int*)(base + K2_POFF + n * 4);
        float2 nd[MM];
#pragma unroll
        for (int m = 0; m < MM; ++m)
          nd[m] = *(const float2*)(base + K2_NOFF + m * 4096 + n * 32 + k * 8);
#pragma unroll
        for (int m = 0; m < MM; ++m) {
          float p = kv.x * qr[m].x + kv.y * qr[m].y
                  + kv.z * qr[m].z + kv.w * qr[m].w
                  + nd[m].x * qw[m].x + nd[m].y * qw[m].y;
          p += __shfl_xor(p, 1); p += __shfl_xor(p, 2);
          const float e = ((pm >> m) & 1u) ? __expf(p) : 0.f;
          ha[m].x = fmaf(e, vv.x, ha[m].x);
          ha[m].y = fmaf(e, vv.y, ha[m].y);
          ha[m].z = fmaf(e, vv.z, ha[m].z);
          ha[m].w = fmaf(e, vv.w, ha[m].w);
          af[m].x = fmaf(e, nd[m].x, af[m].x);
          af[m].y = fmaf(e, nd[m].y, af[m].y);
          ls += e;
        }
      }
    }
    VMCNT0();                          // next tile staged
    __builtin_amdgcn_s_barrier();      // all waves done with cur
  }

  // wave butterfly across the 16 groups (k-slot preserved by xor>=4)
#pragma unroll
  for (int off = 4; off <= 32; off <<= 1) {
#pragma unroll
    for (int m = 0; m < MM; ++m) {
      ha[m].x += __shfl_xor(ha[m].x, off);
      ha[m].y += __shfl_xor(ha[m].y, off);
      ha[m].z += __shfl_xor(ha[m].z, off);
      ha[m].w += __shfl_xor(ha[m].w, off);
      af[m].x += __shfl_xor(af[m].x, off);
      af[m].y += __shfl_xor(af[m].y, off);
    }
    ls += __shfl_xor(ls, off);
  }
  if (lane < 4) {
#pragma unroll
    for (int m = 0; m < MM; ++m) {
      *(float4*)(&redh[w][m][4 * k]) = ha[m];
      *(float2*)(&redaf[w][m][2 * k]) = af[m];
    }
    if (k == 0) reds[w] = ls;
  }
  __syncthreads();
  float* P = part + (size_t)(b * HH + h) * 128;
  if (t < 80) {
    const int m = t >> 4, kk = t & 15;
    P[t] = redh[0][m][kk] + redh[1][m][kk] + redh[2][m][kk] + redh[3][m][kk];
  } else if (t < 120) {
    const int r = t - 80, m = r >> 3, f = r & 7;
    P[80 + r] = redaf[0][m][f] + redaf[1][m][f] + redaf[2][m][f] + redaf[3][m][f];
  } else if (t == 120) {
    P[120] = reds[0] + reds[1] + reds[2] + reds[3];
  }
}

// ---------------- k3: per (b,chunk). Fused: combine records -> conc -> fq,fw
// then streaming logits -> e-values. part: one 128-float record per (b,h).
__global__ __launch_bounds__(512) void k3_logits(
    const float* __restrict__ ndf, const float* __restrict__ lK,
    const unsigned int* __restrict__ pmask, const float* __restrict__ part,
    const float* __restrict__ wpns, const float* __restrict__ po,
    float* __restrict__ out, float* __restrict__ stats)
{
  const int b = blockIdx.x >> 3;
  const int c = blockIdx.x & 7;
  const int t = threadIdx.x;

  __shared__ float pos[DD][129];   // stride 129: conflict-free column reads
  __shared__ float rgs[HH];
  __shared__ float afs[HH][MM][8];
  __shared__ float cs[MM][DD];
  __shared__ float fqs[MM][DD];
  __shared__ float fw[MM][8];
  __shared__ float wred[8];

  for (int i = t; i < DD * DD / 4; i += 512) {
    const float4 v = ((const float4*)po)[i];
    const int r = (i * 4) >> 7, cc = (i * 4) & 127;
    pos[r][cc] = v.x; pos[r][cc + 1] = v.y; pos[r][cc + 2] = v.z; pos[r][cc + 3] = v.w;
  }
  const float* pb = part + (size_t)b * HH * 128;
  if (t < HH) rgs[t] = 1.f / pb[t * 128 + 120];
  if (t < HH * MM * 8) {
    const int h = t / 40, r = t % 40;
    afs[h][r >> 3][r & 7] = pb[h * 128 + 80 + r];
  }
  __syncthreads();
  for (int idx = t; idx < MM * DD; idx += 512) {
    const int m = idx >> 7, d = idx & 127, h = d >> 4;
    const float a = pb[h * 128 + m * 16 + (d & 15)];
    float cf = 0.f;
#pragma unroll
    for (int f = 0; f < 8; ++f) cf = fmaf(wpns[d * 8 + f], afs[h][m][f], cf);
    cs[m][d] = (a + cf) * rgs[h];
  }
  __syncthreads();
  for (int idx = t; idx < MM * DD; idx += 512) {
    const int m = idx >> 7, d = idx & 127;
    float acc = 0.f;
#pragma unroll 8
    for (int j = 0; j < DD; ++j) acc = fmaf(cs[m][j], pos[d][j], acc);
    fqs[m][d] = acc * INV_SQRT_D;
  }
  __syncthreads();
  if (t < MM * 8) {
    const int m = t >> 3, f = t & 7;
    float acc = 0.f;
#pragma unroll 16
    for (int d = 0; d < DD; ++d) acc = fmaf(fqs[m][d], wpns[(2 * DD + d) * 8 + f], acc);
    fw[m][f] = acc;
  }
  __syncthreads();

  // ---- streaming logits (16-lane shfl-dot, direct exp)
  const int k = t & 15, gid = t >> 4;   // 32 groups of 16 lanes
  const int n0 = c * CH3;
  float4 fqr[MM][2];
  float fwr[MM];
#pragma unroll
  for (int m = 0; m < MM; ++m) {
    fqr[m][0] = *(const float4*)(&fqs[m][8 * k]);
    fqr[m][1] = *(const float4*)(&fqs[m][8 * k + 4]);
    fwr[m] = fw[m][k & 7];
  }
  float lsum = 0.f;

#pragma unroll
  for (int i = 0; i < 4; ++i) {
    const int nl = gid + 32 * i;
    const bool valid = (nl < CH3);          // group-uniform
    const int n = n0 + (valid ? nl : 0);
    const unsigned int pm = valid ? pmask[b * NN + n] : 0u;
    const float* lkr = lK + ((size_t)b * NN + n) * DD;
    const float4 l0 = *(const float4*)(lkr + 8 * k);
    const float4 l1 = *(const float4*)(lkr + 8 * k + 4);
    float ndv[MM];
#pragma unroll
    for (int m = 0; m < MM; ++m)
      ndv[m] = (k < 8) ? ndf[((size_t)(b * MM + m) * NN + n) * 8 + k] : 0.f;
#pragma unroll
    for (int m = 0; m < MM; ++m) {
      float p = l0.x * fqr[m][0].x + l0.y * fqr[m][0].y
              + l0.z * fqr[m][0].z + l0.w * fqr[m][0].w
              + l1.x * fqr[m][1].x + l1.y * fqr[m][1].y
              + l1.z * fqr[m][1].z + l1.w * fqr[m][1].w
              + ndv[m] * fwr[m];
      p += __shfl_xor(p, 1); p += __shfl_xor(p, 2);
      p += __shfl_xor(p, 4); p += __shfl_xor(p, 8);
      const float e = ((pm >> m) & 1u) ? __expf(tanh_fast(p) * 10.f) : 0.f;
      if (valid) {
        lsum += e;
        if (k == 0) out[(size_t)(b * MM + m) * NN + n] = e;
      }
    }
  }
  lsum += __shfl_xor(lsum, 16);
  lsum += __shfl_xor(lsum, 32);
  if ((t & 63) == 0) wred[t >> 6] = lsum;
  __syncthreads();
  if (t == 0) {
    float s = 0.f;
#pragma unroll
    for (int w2 = 0; w2 < 8; ++w2) s += wred[w2];
    stats[b * NC3 + c] = s;
  }
}

// ---------------- k4: per (b,m) scale row by 1/sum
__global__ __launch_bounds__(256) void k4_probs(
    const float* __restrict__ stats, float* __restrict__ out)
{
  const int bm = blockIdx.x;
  const int b = bm / MM;
  const int t = threadIdx.x;
  float s = 0.f;
#pragma unroll
  for (int c = 0; c < NC3; ++c) s += stats[b * NC3 + c];
  const float scale = 1.f / s;
  if (t < 250) {
    float4* p = (float4*)(out + (size_t)bm * NN);
    float4 v = p[t];
    v.x *= scale; v.y *= scale; v.z *= scale; v.w *= scale;
    p[t] = v;
  }
}

extern "C" void kernel_launch(void* const* d_in, const int* in_sizes, int n_in,
                              void* d_out, int out_size, void* d_ws, size_t ws_size,
                              hipStream_t stream) {
  // d_in[0] = node_embeddings: dead input, never read.
  const float* fc   = (const float*)d_in[1];
  const float* pne  = (const float*)d_in[2];
  const float* ndf  = (const float*)d_in[3];
  const float* vdf  = (const float*)d_in[4];
  const float* gV   = (const float*)d_in[5];
  const float* gK   = (const float*)d_in[6];
  const float* lK   = (const float*)d_in[7];
  const int*   mask = (const int*)d_in[8];
  const float* wpcv = (const float*)d_in[9];
  const float* wpns = (const float*)d_in[10];
  const float* po   = (const float*)d_in[11];

  float* q_ws  = (float*)d_ws;                        // 40960
  float* qw_ws = q_ws + BB * MM * DD;                 // 20480
  float* part  = qw_ws + BB * HH * 40;                // 64*8*128 = 65536
  float* stats = part + (size_t)BB * HH * 128;        // 512
  unsigned int* pmask = (unsigned int*)(stats + BB * NC3);  // 64000 u32
  float* out   = (float*)d_out;

  k1_query<<<BB * 4 + BB, 256, 0, stream>>>(fc, pne, vdf, wpcv, wpns, mask,
                                            q_ws, qw_ws, pmask);
  k2_attn<<<HH * BB, 256, 0, stream>>>(ndf, gV, gK, pmask, q_ws, qw_ws, part);
  k3_logits<<<BB * NC3, 512, 0, stream>>>(ndf, lK, pmask, part, wpns, po, out, stats);
  k4_probs<<<BB * MM, 256, 0, stream>>>(stats, out);
}